// Round 26
// baseline (4313.460 us; speedup 1.0000x reference)
//
#include <hip/hip_runtime.h>
#include <hip/hip_bf16.h>
#include <math.h>

typedef unsigned short ushort_t;
typedef unsigned int uint_t;
typedef __attribute__((ext_vector_type(8))) short short8;
typedef __attribute__((ext_vector_type(4))) float f32x4;

// Problem constants
#define BATCH 64
#define CHN 3
#define IMG 224
#define PATCH 16
#define HP 14
#define NPATCH 196
#define RSEG 196
#define DMODEL 384
#define HEADS 6
#define HD 64
#define DEPTH 12
#define MLPD 1536
#define CLS 1000
#define WIN 4
#define SEQ 197
#define PIX (IMG*IMG)
#define PATCHK (CHN*PATCH*PATCH)  // 768
#define CPARTS 16                 // centroid blocks per image
#define PPP (PIX / CPARTS)        // 3136 pixels per part
#define HIDP 1544                 // padded hid row stride (bank spread)

__device__ __forceinline__ ushort_t f2bf(float f) {
  uint_t u = __float_as_uint(f);
  u += 0x7FFFu + ((u >> 16) & 1u);
  return (ushort_t)(u >> 16);
}
__device__ __forceinline__ float bf2f(ushort_t u) {
  return __uint_as_float((uint_t)u << 16);
}
// gelu-tanh via hardware exp2: gelu = x*t/(t+1), t = e^{2z}, z clamped.
__device__ __forceinline__ float gelu_tanh(float x) {
  float z = 0.7978845608028654f * (x + 0.044715f * x * x * x);
  z = fminf(fmaxf(z, -15.f), 15.f);
  float t = exp2f(2.8853900817779268f * z);  // e^{2z}
  return x * t / (t + 1.f);
}
// Bijective XCD swizzle (m204)
__device__ __forceinline__ int xcd_swizzle(int bid, int nwg) {
  int q = nwg >> 3, r = nwg & 7;
  int xcd = bid & 7, idx = bid >> 3;
  int start = (xcd < r) ? xcd * (q + 1) : r * (q + 1) + (xcd - r) * q;
  return start + idx;
}
// 16-dim bf16 dot product from two 32B-aligned pointers
__device__ __forceinline__ float dot16bf(const ushort_t* a, const ushort_t* b) {
  const uint_t* a32 = (const uint_t*)a;
  const uint_t* b32 = (const uint_t*)b;
  float acc = 0.f;
#pragma unroll
  for (int w = 0; w < 8; w++) {
    uint_t ka = a32[w], kb = b32[w];
    acc += bf2f((ushort_t)(ka & 0xffff)) * bf2f((ushort_t)(kb & 0xffff));
    acc += bf2f((ushort_t)(ka >> 16)) * bf2f((ushort_t)(kb >> 16));
  }
  return acc;
}

// ---------------------------------------------------------------------------
// Weight convert+transpose: W[L][K][N] f32 -> Wt[L][N][K] bf16
__global__ __launch_bounds__(256) void convtrans_kernel(
    const float* __restrict__ W, ushort_t* __restrict__ Wt, int K, int N) {
  __shared__ float t[32][33];
  int k0 = blockIdx.y * 32, n0 = blockIdx.x * 32;
  const float* Wl = W + (size_t)blockIdx.z * K * N;
  ushort_t* Wtl = Wt + (size_t)blockIdx.z * K * N;
  int tx = threadIdx.x & 31, ty = threadIdx.x >> 5;  // 32 x 8
#pragma unroll
  for (int i = 0; i < 32; i += 8)
    t[ty + i][tx] = Wl[(size_t)(k0 + ty + i) * N + n0 + tx];
  __syncthreads();
#pragma unroll
  for (int i = 0; i < 32; i += 8)
    Wtl[(size_t)(n0 + ty + i) * K + k0 + tx] = f2bf(t[tx][ty + i]);
}

// ---------------------------------------------------------------------------
// Patchify v2 -> bf16, 4 elems/thread (float4 in, 2x packed-u32 out)
__global__ __launch_bounds__(256) void patchify_kernel(
    const float* __restrict__ x, ushort_t* __restrict__ xp, int total4) {
  int idx = blockIdx.x * 256 + threadIdx.x;
  if (idx >= total4) return;
  int kq = idx % (PATCHK / 4);
  int m = idx / (PATCHK / 4);
  int n = m % NPATCH;
  int b = m / NPATCH;
  int hi = n / HP, wi = n % HP;
  int k = kq * 4;
  int c = k >> 8;
  int rem = k & 255;
  int pi = rem >> 4, pj = rem & 15;
  int row = hi * PATCH + pi, col = wi * PATCH + pj;
  f32x4 v = *(const f32x4*)&x[(((size_t)b * CHN + c) * IMG + row) * IMG + col];
  uint_t p0 = (uint_t)f2bf(v[0]) | ((uint_t)f2bf(v[1]) << 16);
  uint_t p1 = (uint_t)f2bf(v[2]) | ((uint_t)f2bf(v[3]) << 16);
  uint_t* dst = (uint_t*)(xp + (size_t)idx * 4);
  dst[0] = p0;
  dst[1] = p1;
}

// ---------------------------------------------------------------------------
// bf16 MFMA GEMM, BK=64, 2-phase double-buffered global_load_lds staging,
// hoisted addressing (R23-validated). XOR-swizzled LDS; bf16 outputs staged
// through LDS (full-line stores). T1 bijective XCD swizzle; T5 setprio.
// OUTMODE: 0 = f32 linear (direct), 1 = bf16 linear, 2 = bf16 qkv-permuted
template <int BMT, bool GELU, bool RESID, int OUTMODE>
__global__ __launch_bounds__(256) void gemm_gl(
    const ushort_t* __restrict__ A, const ushort_t* __restrict__ Bt,
    const float* __restrict__ bias, const float* __restrict__ resid,
    void* __restrict__ Cout, int M, int N, int K, int gx) {
  constexpr int AWS = BMT * 2;             // A 16B-slots per wave (BK=64)
  constexpr int AI = AWS / 64;             // A gload instrs per wave
  constexpr int MF = 4;
  constexpr int NF = (BMT == 128) ? 4 : 2;
  constexpr int BUF_U = (BMT + 128) * 64;     // one staging buffer (ushorts)
  constexpr int CS_U = BMT * 136;             // C-stage ushorts
  constexpr int SMEM_U = (2 * BUF_U > CS_U) ? 2 * BUF_U : CS_U;
  __shared__ __align__(16) ushort_t smem[SMEM_U];
  int tid = threadIdx.x;
  int wave = tid >> 6, lane = tid & 63;
  int flat = xcd_swizzle(blockIdx.x, gridDim.x);
  int bx = flat % gx, by = flat / gx;
  int bm = by * BMT, bn = bx * 128;
  int wr = (BMT == 128) ? (wave >> 1) * 64 : 0;
  int wc = (BMT == 128) ? (wave & 1) * 64 : wave * 32;
  f32x4 acc[MF][NF];
#pragma unroll
  for (int m = 0; m < MF; m++)
#pragma unroll
    for (int n = 0; n < NF; n++)
#pragma unroll
      for (int e = 0; e < 4; e++) acc[m][n][e] = 0.f;

  int r = lane & 15;
  int cfrag = lane >> 4;  // logical slot within a 4-slot (32-dim) group

  // ---- hoisted staging addresses (advance by +64 elems per K-step) ----
  const ushort_t* asrc[AI];
  uint_t adst[AI];
#pragma unroll
  for (int j = 0; j < AI; j++) {
    int s = wave * AWS + j * 64 + lane;
    int row = s >> 3;
    int cp = s & 7;
    int c = cp ^ ((row >> 1) & 7);  // inverse-swizzle source
    asrc[j] = A + (size_t)(bm + row) * K + c * 8;
    adst[j] = (uint_t)(wave * AWS + j * 64) * 8;
  }
  const ushort_t* bsrc[4];
  uint_t bdst[4];
#pragma unroll
  for (int j = 0; j < 4; j++) {
    int s = wave * 256 + j * 64 + lane;
    int row = s >> 3;
    int cp = s & 7;
    int c = cp ^ ((row >> 1) & 7);
    bsrc[j] = Bt + (size_t)(bn + row) * K + c * 8;
    bdst[j] = (uint_t)(BMT * 64) + (uint_t)(wave * 256 + j * 64) * 8;
  }
  // ---- hoisted fragment LDS offsets (ushort indices within a buffer) ----
  uint_t aoff[2][MF], boff[2][NF];
#pragma unroll
  for (int kk = 0; kk < 2; kk++) {
#pragma unroll
    for (int m = 0; m < MF; m++) {
      int row = wr + m * 16 + r;
      int sl = (kk * 4 + cfrag) ^ ((row >> 1) & 7);
      aoff[kk][m] = (uint_t)(row * 64 + sl * 8);
    }
#pragma unroll
    for (int n = 0; n < NF; n++) {
      int row = wc + n * 16 + r;
      int sl = (kk * 4 + cfrag) ^ ((row >> 1) & 7);
      boff[kk][n] = (uint_t)(BMT * 64 + row * 64 + sl * 8);
    }
  }

  auto STAGE = [&](int buf) {
    ushort_t* base = smem + buf * BUF_U;
#pragma unroll
    for (int j = 0; j < AI; j++)
      __builtin_amdgcn_global_load_lds(
          (const __attribute__((address_space(1))) void*)asrc[j],
          (__attribute__((address_space(3))) void*)(base + adst[j]), 16, 0, 0);
#pragma unroll
    for (int j = 0; j < 4; j++)
      __builtin_amdgcn_global_load_lds(
          (const __attribute__((address_space(1))) void*)bsrc[j],
          (__attribute__((address_space(3))) void*)(base + bdst[j]), 16, 0, 0);
  };
  auto ADVANCE = [&]() {
#pragma unroll
    for (int j = 0; j < AI; j++) asrc[j] += 64;
#pragma unroll
    for (int j = 0; j < 4; j++) bsrc[j] += 64;
  };

  STAGE(0);
  ADVANCE();
  __syncthreads();  // buf0 ready
  int cur = 0;
  for (int k0 = 0; k0 < K; k0 += 64) {
    if (k0 + 64 < K) {
      STAGE(cur ^ 1);  // async prefetch next tile
      ADVANCE();
    }
    ushort_t* base = smem + cur * BUF_U;
#pragma unroll
    for (int kk = 0; kk < 2; kk++) {
      short8 af[MF], bfr[NF];
#pragma unroll
      for (int m = 0; m < MF; m++)
        af[m] = *(const short8*)(base + aoff[kk][m]);
#pragma unroll
      for (int n = 0; n < NF; n++)
        bfr[n] = *(const short8*)(base + boff[kk][n]);
      __builtin_amdgcn_s_setprio(1);
#pragma unroll
      for (int m = 0; m < MF; m++)
#pragma unroll
        for (int n = 0; n < NF; n++)
          acc[m][n] = __builtin_amdgcn_mfma_f32_16x16x32_bf16(
              af[m], bfr[n], acc[m][n], 0, 0, 0);
      __builtin_amdgcn_s_setprio(0);
    }
    __syncthreads();  // drains prefetch (vmcnt0) + LDS-read fence
    cur ^= 1;
  }
  int q4 = (lane >> 4) * 4;
  if (OUTMODE == 0) {
    // direct f32 stores (16 consecutive lanes = 64B full sectors)
#pragma unroll
    for (int n = 0; n < NF; n++) {
      int col = bn + wc + n * 16 + r;
      float bi = bias[col];
#pragma unroll
      for (int m = 0; m < MF; m++) {
#pragma unroll
        for (int e = 0; e < 4; e++) {
          int row = bm + wr + m * 16 + q4 + e;
          if (row < M) {
            float v = acc[m][n][e] + bi;
            if (GELU) v = gelu_tanh(v);
            if (RESID) v += resid[(size_t)row * N + col];
            ((float*)Cout)[(size_t)row * N + col] = v;
          }
        }
      }
    }
  } else {
    // stage C tile (BMT x 128 bf16) in LDS, then wide coalesced stores.
    ushort_t* Cs = smem;
#pragma unroll
    for (int n = 0; n < NF; n++) {
      int lc = wc + n * 16 + r;
      float bi = bias[bn + lc];
#pragma unroll
      for (int m = 0; m < MF; m++) {
#pragma unroll
        for (int e = 0; e < 4; e++) {
          int lr = wr + m * 16 + q4 + e;
          float v = acc[m][n][e] + bi;
          if (GELU) v = gelu_tanh(v);
          if (RESID) v += resid[(size_t)(bm + lr) * N + bn + lc];
          Cs[lr * 136 + lc] = f2bf(v);
        }
      }
    }
    __syncthreads();
    constexpr int CHUNKS = BMT * 16;  // 16B chunks in the tile
#pragma unroll
    for (int c = 0; c < CHUNKS / 256; c++) {
      int id = c * 256 + tid;
      int row = id >> 4, ch = id & 15;
      int grow = bm + row;
      if (grow < M) {
        short8 val = *(const short8*)(Cs + row * 136 + ch * 8);
        int gcol = bn + ch * 8;
        if (OUTMODE == 1) {
          *(short8*)((ushort_t*)Cout + (size_t)grow * N + gcol) = val;
        } else {
          int b_ = grow / SEQ, t_ = grow - b_ * SEQ;
          int which = gcol / DMODEL;
          int hcol = gcol - which * DMODEL;
          int hh = hcol >> 6, d0 = hcol & 63;
          *(short8*)((ushort_t*)Cout +
                     ((((size_t)b_ * 3 + which) * HEADS + hh) * SEQ + t_) * 64 +
                     d0) = val;
        }
      }
    }
  }
}

// ---------------------------------------------------------------------------
// FUSED MLP: h += gelu(z @ W1 + b1) @ W2 + b2, per 16-row tile.
// Phase 1: hid[16][1536] bf16 in LDS (stride HIDP for bank spread); A/B frags
// read per-lane from global (z 9.7MB, W1 1.2MB: L2-resident). Phase 2: A from
// LDS, B (W2, 1.2MB L2-hot) per-lane global. MFMA fragment mappings identical
// to gemm_gl (validated): A row=lane&15,k=(lane>>4)*8; C col=lane&15,
// row=(lane>>4)*4+e. Grid = MT/16 = 788 exact (no tails).
__global__ __launch_bounds__(256) void fused_mlp_kernel(
    const ushort_t* __restrict__ z, const ushort_t* __restrict__ W1t,
    const float* __restrict__ b1, const ushort_t* __restrict__ W2t,
    const float* __restrict__ b2, float* __restrict__ h) {
  __shared__ __align__(16) ushort_t hid[16 * HIDP];  // 49408 B
  int tid = threadIdx.x;
  int wave = tid >> 6, lane = tid & 63;
  int bm = (int)blockIdx.x * 16;
  int r = lane & 15;
  int koff = (lane >> 4) * 8;
  int q4 = (lane >> 4) * 4;

  // ---- phase 1: hid = gelu(z @ W1 + b1), 12 chunks of 128 cols ----
  for (int nch = 0; nch < 12; nch++) {
    int colbase = nch * 128 + wave * 32;
    f32x4 acc0 = {0.f, 0.f, 0.f, 0.f};
    f32x4 acc1 = {0.f, 0.f, 0.f, 0.f};
#pragma unroll
    for (int ks = 0; ks < 12; ks++) {
      short8 a = *(const short8*)(z + (size_t)(bm + r) * DMODEL + ks * 32 + koff);
      short8 w0 = *(const short8*)(W1t + (size_t)(colbase + r) * DMODEL + ks * 32 + koff);
      short8 w1 = *(const short8*)(W1t + (size_t)(colbase + 16 + r) * DMODEL + ks * 32 + koff);
      acc0 = __builtin_amdgcn_mfma_f32_16x16x32_bf16(a, w0, acc0, 0, 0, 0);
      acc1 = __builtin_amdgcn_mfma_f32_16x16x32_bf16(a, w1, acc1, 0, 0, 0);
    }
    int c0 = colbase + r, c1 = colbase + 16 + r;
    float bi0 = b1[c0], bi1 = b1[c1];
#pragma unroll
    for (int e = 0; e < 4; e++) {
      int row = q4 + e;
      hid[row * HIDP + c0] = f2bf(gelu_tanh(acc0[e] + bi0));
      hid[row * HIDP + c1] = f2bf(gelu_tanh(acc1[e] + bi1));
    }
  }
  __syncthreads();  // hid complete across all waves

  // ---- phase 2: out = hid @ W2 + b2 + h; wave owns 96 cols (6 frags) ----
  int cbase = wave * 96;
  f32x4 acc[6];
#pragma unroll
  for (int f = 0; f < 6; f++)
#pragma unroll
    for (int e = 0; e < 4; e++) acc[f][e] = 0.f;
  for (int ks = 0; ks < 48; ks++) {
    short8 a = *(const short8*)(hid + r * HIDP + ks * 32 + koff);
#pragma unroll
    for (int f = 0; f < 6; f++) {
      short8 w = *(const short8*)(W2t + (size_t)(cbase + f * 16 + r) * MLPD +
                                  ks * 32 + koff);
      acc[f] = __builtin_amdgcn_mfma_f32_16x16x32_bf16(a, w, acc[f], 0, 0, 0);
    }
  }
#pragma unroll
  for (int f = 0; f < 6; f++) {
    int col = cbase + f * 16 + r;
    float bi = b2[col];
#pragma unroll
    for (int e = 0; e < 4; e++) {
      int row = bm + q4 + e;
      float* hp = h + (size_t)row * DMODEL + col;
      *hp = *hp + acc[f][e] + bi;
    }
  }
}

// ---------------------------------------------------------------------------
// Zero the centroid accumulator (graph-safe)
__global__ __launch_bounds__(256) void zeroacc_kernel(int* __restrict__ g,
                                                      int n) {
  int i = blockIdx.x * 256 + threadIdx.x;
  if (i < n) g[i] = 0;
}

// ---------------------------------------------------------------------------
// Centroid v2a: partial histograms, 16 blocks per image, int atomics (determ.)
__global__ __launch_bounds__(256) void centroid_part_kernel(
    const int* __restrict__ seg, int* __restrict__ gacc) {
  __shared__ int cnt[RSEG], si[RSEG], sj[RSEG];
  int b = blockIdx.x, part = blockIdx.y, tid = threadIdx.x;
  for (int r = tid; r < RSEG; r += 256) { cnt[r] = 0; si[r] = 0; sj[r] = 0; }
  __syncthreads();
  const int* s = seg + (size_t)b * PIX;
  int p0 = part * PPP;
  for (int p = p0 + tid; p < p0 + PPP; p += 256) {
    int r = s[p];
    int i = p / IMG, j = p % IMG;
    atomicAdd(&cnt[r], 1);
    atomicAdd(&si[r], i);
    atomicAdd(&sj[r], j);
  }
  __syncthreads();
  for (int r = tid; r < RSEG; r += 256) {
    int c = cnt[r];
    if (c | si[r] | sj[r]) {
      int* g = gacc + ((size_t)b * RSEG + r) * 3;
      atomicAdd(&g[0], c);
      atomicAdd(&g[1], si[r]);
      atomicAdd(&g[2], sj[r]);
    }
  }
}
// Centroid v2b: finalize
__global__ __launch_bounds__(256) void centroid_fin_kernel(
    const int* __restrict__ gacc, float* __restrict__ cent) {
  int b = blockIdx.x, tid = threadIdx.x;
  for (int r = tid; r < RSEG; r += 256) {
    const int* g = gacc + ((size_t)b * RSEG + r) * 3;
    int c = g[0];
    float cx = 0.5f, cy = 0.5f;
    if (c > 0) {
      cx = ((float)g[2] / (float)IMG) / (float)c;
      cy = ((float)g[1] / (float)IMG) / (float)c;
    }
    cent[((size_t)b * RSEG + r) * 2 + 0] = cx;
    cent[((size_t)b * RSEG + r) * 2 + 1] = cy;
  }
}

// ---------------------------------------------------------------------------
// patch_seg[b,n] = seg[b, 8+hi*16, 8+wi*16]
__global__ __launch_bounds__(256) void patchseg_kernel(
    const int* __restrict__ seg, int* __restrict__ pseg) {
  int idx = blockIdx.x * 256 + threadIdx.x;
  if (idx >= BATCH * NPATCH) return;
  int n = idx % NPATCH, b = idx / NPATCH;
  int hi = n / HP, wi = n % HP;
  pseg[idx] = seg[(size_t)b * PIX + (8 + hi * PATCH) * IMG + (8 + wi * PATCH)];
}

// ---------------------------------------------------------------------------
// Build CSR lists of patches per (b, r): deterministic serial counting sort.
__global__ __launch_bounds__(64) void buildlists_kernel(
    const int* __restrict__ pseg, int* __restrict__ starts,
    int* __restrict__ lists) {
  __shared__ int cnt[RSEG];
  int b = blockIdx.x;
  if (threadIdx.x != 0) return;
  const int* ps = pseg + b * NPATCH;
  for (int r = 0; r < RSEG; r++) cnt[r] = 0;
  for (int n = 0; n < NPATCH; n++) cnt[ps[n]]++;
  int run = 0;
  int* st = starts + b * (RSEG + 1);
  for (int r = 0; r < RSEG; r++) {
    st[r] = run;
    int c = cnt[r];
    cnt[r] = run;  // becomes cursor
    run += c;
  }
  st[RSEG] = run;
  int* li = lists + b * NPATCH;
  for (int n = 0; n < NPATCH; n++) {
    int r = ps[n];
    li[cnt[r]++] = n;
  }
}

// ---------------------------------------------------------------------------
// Pool + assemble via CSR lists (avg 1 patch per segment).
__global__ __launch_bounds__(384) void pool_assemble_kernel(
    const float* __restrict__ emb, const float* __restrict__ cent,
    const int* __restrict__ starts, const int* __restrict__ lists,
    const float* __restrict__ cls_token, const float* __restrict__ cls_pos,
    const float* __restrict__ pos_W, const float* __restrict__ pos_b,
    float* __restrict__ h) {
  int t = blockIdx.x;
  int b = t / SEQ, s = t % SEQ;
  int d = threadIdx.x;
  float out;
  if (s == 0) {
    out = cls_token[d] + cls_pos[d];
  } else {
    int r = s - 1;
    int st = starts[b * (RSEG + 1) + r];
    int en = starts[b * (RSEG + 1) + r + 1];
    float acc = 0.f;
    for (int i = st; i < en; i++) {
      int n = lists[b * NPATCH + i];
      acc += emb[((size_t)b * NPATCH + n) * DMODEL + d];
    }
    int cnt = en - st;
    float pooled = acc / (float)(cnt > 0 ? cnt : 1);
    float cx = cent[((size_t)b * RSEG + r) * 2 + 0];
    float cy = cent[((size_t)b * RSEG + r) * 2 + 1];
    out = pooled + cx * pos_W[d] + cy * pos_W[DMODEL + d] + pos_b[d];
  }
  h[(size_t)t * DMODEL + d] = out;
}

// ---------------------------------------------------------------------------
// LayerNorm v2: one WAVE per row, 4 rows/block, float2 loads, shfl-only
// reduce (no LDS, no barrier). Grid = rows/4.
template <bool OUTBF16>
__global__ __launch_bounds__(256) void ln_kernel(
    const float* __restrict__ in, void* __restrict__ out,
    const float* __restrict__ w, const float* __restrict__ b, int inStride) {
  int wave = threadIdx.x >> 6, lane = threadIdx.x & 63;
  int row = blockIdx.x * 4 + wave;
  const float* xr = in + (size_t)row * inStride;
  float2 v0 = *(const float2*)(xr + lane * 2);
  float2 v1 = *(const float2*)(xr + 128 + lane * 2);
  float2 v2 = *(const float2*)(xr + 256 + lane * 2);
  float s = v0.x + v0.y + v1.x + v1.y + v2.x + v2.y;
  float s2 = v0.x * v0.x + v0.y * v0.y + v1.x * v1.x + v1.y * v1.y +
             v2.x * v2.x + v2.y * v2.y;
#pragma unroll
  for (int off = 32; off; off >>= 1) {
    s += __shfl_xor(s, off);
    s2 += __shfl_xor(s2, off);
  }
  float m = s / (float)DMODEL;
  float var = s2 / (float)DMODEL - m * m;
  float rs = rsqrtf(var + 1e-5f);
#pragma unroll
  for (int i = 0; i < 3; i++) {
    int d0 = i * 128 + lane * 2;
    float x0 = (i == 0) ? v0.x : (i == 1) ? v1.x : v2.x;
    float x1 = (i == 0) ? v0.y : (i == 1) ? v1.y : v2.y;
    float o0 = (x0 - m) * rs * w[d0] + b[d0];
    float o1 = (x1 - m) * rs * w[d0 + 1] + b[d0 + 1];
    if (OUTBF16) {
      uint_t pack = (uint_t)f2bf(o0) | ((uint_t)f2bf(o1) << 16);
      *(uint_t*)((ushort_t*)out + (size_t)row * DMODEL + d0) = pack;
    } else {
      float2 pk = {o0, o1};
      *(float2*)((float*)out + (size_t)row * DMODEL + d0) = pk;
    }
  }
}

// ---------------------------------------------------------------------------
// Banded attention v5: 4 queries per wave, register-cached K/V window.
__global__ __launch_bounds__(256) void attn_kernel(
    const ushort_t* __restrict__ qkvp, ushort_t* __restrict__ o) {
  int wave = threadIdx.x >> 6, lane = threadIdx.x & 63;
  int gi = blockIdx.x * 4 + wave;  // group index 0..51
  int hh = blockIdx.y, b = blockIdx.z;
  const size_t hstride = (size_t)HEADS * SEQ * 64;
  size_t base0 = ((size_t)b * 3 * HEADS + hh) * SEQ * 64;
  const ushort_t* Qh = qkvp + base0;
  const ushort_t* Kh = qkvp + base0 + hstride;
  const ushort_t* Vh = qkvp + base0 + 2 * hstride;
  if (gi < 49) {
    int q0 = 1 + gi * 4;
    int base = q0 - 4;
    if (base < 1) base = 1;
    int row = lane >> 2, dq = lane & 3;
    int key = (row == 0) ? 0 : base + row - 1;
    bool rowvalid = (key <= 196);
    int kaddr = rowvalid ? key : 196;  // clamp for safe address
    const uint_t* kp = (const uint_t*)(Kh + (size_t)kaddr * 64 + dq * 16);
    uint_t kf[8];
#pragma unroll
    for (int w = 0; w < 8; w++) kf[w] = kp[w];
    float v[16];
#pragma unroll
    for (int r = 0; r < 16; r++) {
      int kr = (r == 0) ? 0 : base + r - 1;
      if (kr > 196) kr = 196;
      v[r] = bf2f(Vh[(size_t)kr * 64 + lane]);
    }
#pragma unroll
    for (int i = 0; i < 4; i++) {
      int qi = q0 + i;
      const uint_t* qp = (const uint_t*)(Qh + (size_t)qi * 64 + dq * 16);
      float part = 0.f;
#pragma unroll
      for (int w = 0; w < 8; w++) {
        uint_t ka = kf[w], qa = qp[w];
        part += bf2f((ushort_t)(ka & 0xffff)) * bf2f((ushort_t)(qa & 0xffff));
        part += bf2f((ushort_t)(ka >> 16)) * bf2f((ushort_t)(qa >> 16));
      }
      part += __shfl_xor(part, 1);
      part += __shfl_xor(part, 2);
      int lo = qi - WIN;
      if (lo < 1) lo = 1;
      int hi = qi + WIN;
      if (hi > 196) hi = 196;
      bool valid = rowvalid && ((key == 0) || (key >= lo && key <= hi));
      float s = valid ? part * 0.125f : -1e30f;
      float mx = s;
      mx = fmaxf(mx, __shfl_xor(mx, 4));
      mx = fmaxf(mx, __shfl_xor(mx, 8));
      mx = fmaxf(mx, __shfl_xor(mx, 16));
      mx = fmaxf(mx, __shfl_xor(mx, 32));
      float p = valid ? expf(s - mx) : 0.f;
      float sum = p;
      sum += __shfl_xor(sum, 4);
      sum += __shfl_xor(sum, 8);
      sum += __shfl_xor(sum, 16);
      sum += __shfl_xor(sum, 32);
      float acc = 0.f;
#pragma unroll
      for (int r = 0; r < 16; r++) acc += __shfl(p, r * 4) * v[r];
      o[((size_t)(b * SEQ + qi)) * DMODEL + hh * HD + lane] = f2bf(acc / sum);
    }
  } else if (gi == 49) {
    const ushort_t* qr = Qh;  // CLS query
    float sc0 = -1e30f, sc1 = -1e30f, sc2 = -1e30f, sc3 = -1e30f;
#pragma unroll
    for (int c = 0; c < 4; c++) {
      int key = c * 64 + lane;
      float s = -1e30f;
      if (key < SEQ) {
        const ushort_t* kr = Kh + (size_t)key * 64;
        float acc = dot16bf(kr, qr) + dot16bf(kr + 16, qr + 16) +
                    dot16bf(kr + 32, qr + 32) + dot16bf(kr + 48, qr + 48);
        s = acc * 0.125f;
      }
      if (c == 0) sc0 = s; else if (c == 1) sc1 = s; else if (c == 2) sc2 = s; else sc3 = s;
    }
    float mx = fmaxf(fmaxf(sc0, sc1), fmaxf(sc2, sc3));
#pragma unroll
    for (int off = 32; off; off >>= 1) mx = fmaxf(mx, __shfl_xor(mx, off));
    float p0 = expf(sc0 - mx), p1 = expf(sc1 - mx);
    float p2 = expf(sc2 - mx), p3 = expf(sc3 - mx);
    float sum = p0 + p1 + p2 + p3;
#pragma unroll
    for (int off = 32; off; off >>= 1) sum += __shfl_xor(sum, off);
    float acc = 0.f;
#pragma unroll
    for (int c = 0; c < 4; c++) {
      float pc = (c == 0) ? p0 : (c == 1) ? p1 : (c == 2) ? p2 : p3;
      int jmax = (c < 3) ? 64 : (SEQ - 192);
      for (int jj = 0; jj < jmax; ++jj) {
        float pt = __shfl(pc, jj);
        acc += pt * bf2f(Vh[(size_t)(c * 64 + jj) * 64 + lane]);
      }
    }
    o[((size_t)(b * SEQ)) * DMODEL + hh * HD + lane] = f2bf(acc / sum);
  }
}

// ---------------------------------------------------------------------------
// Head
__global__ __launch_bounds__(256) void head_kernel(
    const float* __restrict__ hn, const float* __restrict__ W,
    const float* __restrict__ bias, float* __restrict__ out) {
  __shared__ float hs[DMODEL];
  int b = blockIdx.y;
  int c = blockIdx.x * 256 + threadIdx.x;
  for (int d = threadIdx.x; d < DMODEL; d += 256)
    hs[d] = hn[(size_t)b * DMODEL + d];
  __syncthreads();
  if (c >= CLS) return;
  float acc = bias[c];
  for (int d = 0; d < DMODEL; d++) acc += hs[d] * W[(size_t)d * CLS + c];
  out[(size_t)b * CLS + c] = acc;
}

// ---------------------------------------------------------------------------
extern "C" void kernel_launch(void* const* d_in, const int* in_sizes, int n_in,
                              void* d_out, int out_size, void* d_ws,
                              size_t ws_size, hipStream_t stream) {
  const float* x = (const float*)d_in[0];
  const int* seg = (const int*)d_in[1];
  const float* patch_W = (const float*)d_in[2];
  const float* patch_b = (const float*)d_in[3];
  const float* cls_token = (const float*)d_in[4];
  const float* pos_W = (const float*)d_in[5];
  const float* pos_b = (const float*)d_in[6];
  const float* cls_pos = (const float*)d_in[7];
  const float* ln1_w = (const float*)d_in[8];
  const float* ln1_b = (const float*)d_in[9];
  const float* qkv_W = (const float*)d_in[10];
  const float* qkv_b = (const float*)d_in[11];
  const float* proj_W = (const float*)d_in[12];
  const float* proj_b = (const float*)d_in[13];
  const float* ln2_w = (const float*)d_in[14];
  const float* ln2_b = (const float*)d_in[15];
  const float* mlp_W1 = (const float*)d_in[16];
  const float* mlp_b1 = (const float*)d_in[17];
  const float* mlp_W2 = (const float*)d_in[18];
  const float* mlp_b2 = (const float*)d_in[19];
  const float* norm_w = (const float*)d_in[20];
  const float* norm_b = (const float*)d_in[21];
  const float* head_W = (const float*)d_in[22];
  const float* head_b = (const float*)d_in[23];
  float* out = (float*)d_out;

  const int M0 = BATCH * NPATCH;  // 12544 = 196*64
  const int MT = BATCH * SEQ;     // 12608 = 197*64

  // ---- workspace layout ----
  char* ws = (char*)d_ws;
  size_t off = 0;
  auto alloc = [&](size_t bytes) { char* p = ws + off; off += (bytes + 255) & ~(size_t)255; return p; };
  ushort_t* patch_Wt = (ushort_t*)alloc((size_t)PATCHK * DMODEL * 2);
  ushort_t* qkv_Wt   = (ushort_t*)alloc((size_t)DEPTH * DMODEL * 3 * DMODEL * 2);
  ushort_t* proj_Wt  = (ushort_t*)alloc((size_t)DEPTH * DMODEL * DMODEL * 2);
  ushort_t* mlp1_Wt  = (ushort_t*)alloc((size_t)DEPTH * DMODEL * MLPD * 2);
  ushort_t* mlp2_Wt  = (ushort_t*)alloc((size_t)DEPTH * MLPD * DMODEL * 2);
  char* big = alloc((size_t)MT * MLPD * 2);          // xp_bf (mlph no longer used)
  ushort_t* xp_bf = (ushort_t*)big;
  ushort_t* qkvb = (ushort_t*)alloc((size_t)MT * 3 * DMODEL * 2);  // permuted
  char* eo = alloc((size_t)M0 * DMODEL * 4);         // emb f32 / attno bf16
  float* emb = (float*)eo;
  ushort_t* attno = (ushort_t*)eo;
  float* h = (float*)alloc((size_t)MT * DMODEL * 4);
  ushort_t* z_bf = (ushort_t*)alloc((size_t)MT * DMODEL * 2);
  float* cent = (float*)alloc((size_t)BATCH * RSEG * 2 * 4);
  float* hn = (float*)alloc((size_t)BATCH * DMODEL * 4);
  int* pseg = (int*)alloc((size_t)BATCH * NPATCH * 4);
  int* starts = (int*)alloc((size_t)BATCH * (RSEG + 1) * 4);
  int* lists = (int*)alloc((size_t)BATCH * NPATCH * 4);
  int* gacc = (int*)alloc((size_t)BATCH * RSEG * 3 * 4);

  // ---- weight conversion+transpose (bf16, [N][K]) ----
  convtrans_kernel<<<dim3(DMODEL / 32, PATCHK / 32, 1), 256, 0, stream>>>(
      patch_W, patch_Wt, PATCHK, DMODEL);
  convtrans_kernel<<<dim3(3 * DMODEL / 32, DMODEL / 32, DEPTH), 256, 0, stream>>>(
      qkv_W, qkv_Wt, DMODEL, 3 * DMODEL);
  convtrans_kernel<<<dim3(DMODEL / 32, DMODEL / 32, DEPTH), 256, 0, stream>>>(
      proj_W, proj_Wt, DMODEL, DMODEL);
  convtrans_kernel<<<dim3(MLPD / 32, DMODEL / 32, DEPTH), 256, 0, stream>>>(
      mlp_W1, mlp1_Wt, DMODEL, MLPD);
  convtrans_kernel<<<dim3(DMODEL / 32, MLPD / 32, DEPTH), 256, 0, stream>>>(
      mlp_W2, mlp2_Wt, MLPD, DMODEL);

  // ---- front-end ----
  {
    int total4 = M0 * PATCHK / 4;
    patchify_kernel<<<(total4 + 255) / 256, 256, 0, stream>>>(x, xp_bf, total4);
  }
  gemm_gl<64, false, false, 0><<<(DMODEL / 128) * (M0 / 64), 256, 0, stream>>>(
      xp_bf, patch_Wt, patch_b, nullptr, emb, M0, DMODEL, PATCHK, DMODEL / 128);
  {
    int n = BATCH * RSEG * 3;
    zeroacc_kernel<<<(n + 255) / 256, 256, 0, stream>>>(gacc, n);
  }
  centroid_part_kernel<<<dim3(BATCH, CPARTS), 256, 0, stream>>>(seg, gacc);
  centroid_fin_kernel<<<BATCH, 256, 0, stream>>>(gacc, cent);
  patchseg_kernel<<<(M0 + 255) / 256, 256, 0, stream>>>(seg, pseg);
  buildlists_kernel<<<BATCH, 64, 0, stream>>>(pseg, starts, lists);
  pool_assemble_kernel<<<MT, 384, 0, stream>>>(emb, cent, starts, lists,
                                               cls_token, cls_pos, pos_W,
                                               pos_b, h);

  // ---- transformer layers ----
  int gy128 = (MT + 127) / 128;  // 99 (tail OOB reads covered by ws layout)
  int gy64 = MT / 64;            // 197 exact
  for (int l = 0; l < DEPTH; l++) {
    ln_kernel<true><<<MT / 4, 256, 0, stream>>>(h, z_bf, ln1_w + l * DMODEL,
                                                ln1_b + l * DMODEL, DMODEL);
    gemm_gl<128, false, false, 2><<<(3 * DMODEL / 128) * gy128, 256, 0, stream>>>(
        z_bf, qkv_Wt + (size_t)l * DMODEL * 3 * DMODEL, qkv_b + l * 3 * DMODEL,
        nullptr, qkvb, MT, 3 * DMODEL, DMODEL, 3 * DMODEL / 128);
    attn_kernel<<<dim3(13, HEADS, BATCH), 256, 0, stream>>>(qkvb, attno);
    gemm_gl<64, false, true, 0><<<(DMODEL / 128) * gy64, 256, 0, stream>>>(
        attno, proj_Wt + (size_t)l * DMODEL * DMODEL, proj_b + l * DMODEL, h,
        h, MT, DMODEL, DMODEL, DMODEL / 128);
    ln_kernel<true><<<MT / 4, 256, 0, stream>>>(h, z_bf, ln2_w + l * DMODEL,
                                                ln2_b + l * DMODEL, DMODEL);
    fused_mlp_kernel<<<MT / 16, 256, 0, stream>>>(
        z_bf, mlp1_Wt + (size_t)l * DMODEL * MLPD, mlp_b1 + l * MLPD,
        mlp2_Wt + (size_t)l * MLPD * DMODEL, mlp_b2 + l * DMODEL, h);
  }
  // ---- final LN (CLS rows only, 64 rows -> 16 blocks) + head ----
  ln_kernel<false><<<BATCH / 4, 256, 0, stream>>>(h, hn, norm_w, norm_b,
                                                  SEQ * DMODEL);
  head_kernel<<<dim3((CLS + 255) / 256, BATCH), 256, 0, stream>>>(
      hn, head_W, head_b, out);
}

// Round 27
// 1915.361 us; speedup vs baseline: 2.2520x; 2.2520x over previous
//
#include <hip/hip_runtime.h>
#include <hip/hip_bf16.h>
#include <math.h>

typedef unsigned short ushort_t;
typedef unsigned int uint_t;
typedef __attribute__((ext_vector_type(8))) short short8;
typedef __attribute__((ext_vector_type(4))) float f32x4;

// Problem constants
#define BATCH 64
#define CHN 3
#define IMG 224
#define PATCH 16
#define HP 14
#define NPATCH 196
#define RSEG 196
#define DMODEL 384
#define HEADS 6
#define HD 64
#define DEPTH 12
#define MLPD 1536
#define CLS 1000
#define WIN 4
#define SEQ 197
#define PIX (IMG*IMG)
#define PATCHK (CHN*PATCH*PATCH)  // 768
#define CPARTS 16                 // centroid blocks per image
#define PPP (PIX / CPARTS)        // 3136 pixels per part

__device__ __forceinline__ ushort_t f2bf(float f) {
  uint_t u = __float_as_uint(f);
  u += 0x7FFFu + ((u >> 16) & 1u);
  return (ushort_t)(u >> 16);
}
__device__ __forceinline__ float bf2f(ushort_t u) {
  return __uint_as_float((uint_t)u << 16);
}
// gelu-tanh via hardware exp2: gelu = x*t/(t+1), t = e^{2z}, z clamped.
__device__ __forceinline__ float gelu_tanh(float x) {
  float z = 0.7978845608028654f * (x + 0.044715f * x * x * x);
  z = fminf(fmaxf(z, -15.f), 15.f);
  float t = exp2f(2.8853900817779268f * z);  // e^{2z}
  return x * t / (t + 1.f);
}
// Bijective XCD swizzle (m204)
__device__ __forceinline__ int xcd_swizzle(int bid, int nwg) {
  int q = nwg >> 3, r = nwg & 7;
  int xcd = bid & 7, idx = bid >> 3;
  int start = (xcd < r) ? xcd * (q + 1) : r * (q + 1) + (xcd - r) * q;
  return start + idx;
}
// 16-dim bf16 dot product from two 32B-aligned pointers
__device__ __forceinline__ float dot16bf(const ushort_t* a, const ushort_t* b) {
  const uint_t* a32 = (const uint_t*)a;
  const uint_t* b32 = (const uint_t*)b;
  float acc = 0.f;
#pragma unroll
  for (int w = 0; w < 8; w++) {
    uint_t ka = a32[w], kb = b32[w];
    acc += bf2f((ushort_t)(ka & 0xffff)) * bf2f((ushort_t)(kb & 0xffff));
    acc += bf2f((ushort_t)(ka >> 16)) * bf2f((ushort_t)(kb >> 16));
  }
  return acc;
}

// ---------------------------------------------------------------------------
// Weight convert+transpose: W[L][K][N] f32 -> Wt[L][N][K] bf16
__global__ __launch_bounds__(256) void convtrans_kernel(
    const float* __restrict__ W, ushort_t* __restrict__ Wt, int K, int N) {
  __shared__ float t[32][33];
  int k0 = blockIdx.y * 32, n0 = blockIdx.x * 32;
  const float* Wl = W + (size_t)blockIdx.z * K * N;
  ushort_t* Wtl = Wt + (size_t)blockIdx.z * K * N;
  int tx = threadIdx.x & 31, ty = threadIdx.x >> 5;  // 32 x 8
#pragma unroll
  for (int i = 0; i < 32; i += 8)
    t[ty + i][tx] = Wl[(size_t)(k0 + ty + i) * N + n0 + tx];
  __syncthreads();
#pragma unroll
  for (int i = 0; i < 32; i += 8)
    Wtl[(size_t)(n0 + ty + i) * K + k0 + tx] = f2bf(t[tx][ty + i]);
}

// ---------------------------------------------------------------------------
// Patchify v2 -> bf16, 4 elems/thread (float4 in, 2x packed-u32 out)
__global__ __launch_bounds__(256) void patchify_kernel(
    const float* __restrict__ x, ushort_t* __restrict__ xp, int total4) {
  int idx = blockIdx.x * 256 + threadIdx.x;
  if (idx >= total4) return;
  int kq = idx % (PATCHK / 4);
  int m = idx / (PATCHK / 4);
  int n = m % NPATCH;
  int b = m / NPATCH;
  int hi = n / HP, wi = n % HP;
  int k = kq * 4;
  int c = k >> 8;
  int rem = k & 255;
  int pi = rem >> 4, pj = rem & 15;
  int row = hi * PATCH + pi, col = wi * PATCH + pj;
  f32x4 v = *(const f32x4*)&x[(((size_t)b * CHN + c) * IMG + row) * IMG + col];
  uint_t p0 = (uint_t)f2bf(v[0]) | ((uint_t)f2bf(v[1]) << 16);
  uint_t p1 = (uint_t)f2bf(v[2]) | ((uint_t)f2bf(v[3]) << 16);
  uint_t* dst = (uint_t*)(xp + (size_t)idx * 4);
  dst[0] = p0;
  dst[1] = p1;
}

// ---------------------------------------------------------------------------
// bf16 MFMA GEMM, BK=64, 2-phase double-buffered global_load_lds staging,
// hoisted addressing (R23-validated). XOR-swizzled LDS; bf16 outputs staged
// through LDS (full-line stores). T1 bijective XCD swizzle; T5 setprio.
// OUTMODE: 0 = f32 linear (direct), 1 = bf16 linear, 2 = bf16 qkv-permuted
template <int BMT, bool GELU, bool RESID, int OUTMODE>
__global__ __launch_bounds__(256) void gemm_gl(
    const ushort_t* __restrict__ A, const ushort_t* __restrict__ Bt,
    const float* __restrict__ bias, const float* __restrict__ resid,
    void* __restrict__ Cout, int M, int N, int K, int gx) {
  constexpr int AWS = BMT * 2;             // A 16B-slots per wave (BK=64)
  constexpr int AI = AWS / 64;             // A gload instrs per wave
  constexpr int MF = 4;
  constexpr int NF = (BMT == 128) ? 4 : 2;
  constexpr int BUF_U = (BMT + 128) * 64;     // one staging buffer (ushorts)
  constexpr int CS_U = BMT * 136;             // C-stage ushorts
  constexpr int SMEM_U = (2 * BUF_U > CS_U) ? 2 * BUF_U : CS_U;
  __shared__ __align__(16) ushort_t smem[SMEM_U];
  int tid = threadIdx.x;
  int wave = tid >> 6, lane = tid & 63;
  int flat = xcd_swizzle(blockIdx.x, gridDim.x);
  int bx = flat % gx, by = flat / gx;
  int bm = by * BMT, bn = bx * 128;
  int wr = (BMT == 128) ? (wave >> 1) * 64 : 0;
  int wc = (BMT == 128) ? (wave & 1) * 64 : wave * 32;
  f32x4 acc[MF][NF];
#pragma unroll
  for (int m = 0; m < MF; m++)
#pragma unroll
    for (int n = 0; n < NF; n++)
#pragma unroll
      for (int e = 0; e < 4; e++) acc[m][n][e] = 0.f;

  int r = lane & 15;
  int cfrag = lane >> 4;  // logical slot within a 4-slot (32-dim) group

  // ---- hoisted staging addresses (advance by +64 elems per K-step) ----
  const ushort_t* asrc[AI];
  uint_t adst[AI];
#pragma unroll
  for (int j = 0; j < AI; j++) {
    int s = wave * AWS + j * 64 + lane;
    int row = s >> 3;
    int cp = s & 7;
    int c = cp ^ ((row >> 1) & 7);  // inverse-swizzle source
    asrc[j] = A + (size_t)(bm + row) * K + c * 8;
    adst[j] = (uint_t)(wave * AWS + j * 64) * 8;
  }
  const ushort_t* bsrc[4];
  uint_t bdst[4];
#pragma unroll
  for (int j = 0; j < 4; j++) {
    int s = wave * 256 + j * 64 + lane;
    int row = s >> 3;
    int cp = s & 7;
    int c = cp ^ ((row >> 1) & 7);
    bsrc[j] = Bt + (size_t)(bn + row) * K + c * 8;
    bdst[j] = (uint_t)(BMT * 64) + (uint_t)(wave * 256 + j * 64) * 8;
  }
  // ---- hoisted fragment LDS offsets (ushort indices within a buffer) ----
  uint_t aoff[2][MF], boff[2][NF];
#pragma unroll
  for (int kk = 0; kk < 2; kk++) {
#pragma unroll
    for (int m = 0; m < MF; m++) {
      int row = wr + m * 16 + r;
      int sl = (kk * 4 + cfrag) ^ ((row >> 1) & 7);
      aoff[kk][m] = (uint_t)(row * 64 + sl * 8);
    }
#pragma unroll
    for (int n = 0; n < NF; n++) {
      int row = wc + n * 16 + r;
      int sl = (kk * 4 + cfrag) ^ ((row >> 1) & 7);
      boff[kk][n] = (uint_t)(BMT * 64 + row * 64 + sl * 8);
    }
  }

  auto STAGE = [&](int buf) {
    ushort_t* base = smem + buf * BUF_U;
#pragma unroll
    for (int j = 0; j < AI; j++)
      __builtin_amdgcn_global_load_lds(
          (const __attribute__((address_space(1))) void*)asrc[j],
          (__attribute__((address_space(3))) void*)(base + adst[j]), 16, 0, 0);
#pragma unroll
    for (int j = 0; j < 4; j++)
      __builtin_amdgcn_global_load_lds(
          (const __attribute__((address_space(1))) void*)bsrc[j],
          (__attribute__((address_space(3))) void*)(base + bdst[j]), 16, 0, 0);
  };
  auto ADVANCE = [&]() {
#pragma unroll
    for (int j = 0; j < AI; j++) asrc[j] += 64;
#pragma unroll
    for (int j = 0; j < 4; j++) bsrc[j] += 64;
  };

  STAGE(0);
  ADVANCE();
  __syncthreads();  // buf0 ready
  int cur = 0;
  for (int k0 = 0; k0 < K; k0 += 64) {
    if (k0 + 64 < K) {
      STAGE(cur ^ 1);  // async prefetch next tile
      ADVANCE();
    }
    ushort_t* base = smem + cur * BUF_U;
#pragma unroll
    for (int kk = 0; kk < 2; kk++) {
      short8 af[MF], bfr[NF];
#pragma unroll
      for (int m = 0; m < MF; m++)
        af[m] = *(const short8*)(base + aoff[kk][m]);
#pragma unroll
      for (int n = 0; n < NF; n++)
        bfr[n] = *(const short8*)(base + boff[kk][n]);
      __builtin_amdgcn_s_setprio(1);
#pragma unroll
      for (int m = 0; m < MF; m++)
#pragma unroll
        for (int n = 0; n < NF; n++)
          acc[m][n] = __builtin_amdgcn_mfma_f32_16x16x32_bf16(
              af[m], bfr[n], acc[m][n], 0, 0, 0);
      __builtin_amdgcn_s_setprio(0);
    }
    __syncthreads();  // drains prefetch (vmcnt0) + LDS-read fence
    cur ^= 1;
  }
  int q4 = (lane >> 4) * 4;
  if (OUTMODE == 0) {
    // direct f32 stores (16 consecutive lanes = 64B full sectors)
#pragma unroll
    for (int n = 0; n < NF; n++) {
      int col = bn + wc + n * 16 + r;
      float bi = bias[col];
#pragma unroll
      for (int m = 0; m < MF; m++) {
#pragma unroll
        for (int e = 0; e < 4; e++) {
          int row = bm + wr + m * 16 + q4 + e;
          if (row < M) {
            float v = acc[m][n][e] + bi;
            if (GELU) v = gelu_tanh(v);
            if (RESID) v += resid[(size_t)row * N + col];
            ((float*)Cout)[(size_t)row * N + col] = v;
          }
        }
      }
    }
  } else {
    // stage C tile (BMT x 128 bf16) in LDS, then wide coalesced stores.
    ushort_t* Cs = smem;
#pragma unroll
    for (int n = 0; n < NF; n++) {
      int lc = wc + n * 16 + r;
      float bi = bias[bn + lc];
#pragma unroll
      for (int m = 0; m < MF; m++) {
#pragma unroll
        for (int e = 0; e < 4; e++) {
          int lr = wr + m * 16 + q4 + e;
          float v = acc[m][n][e] + bi;
          if (GELU) v = gelu_tanh(v);
          if (RESID) v += resid[(size_t)(bm + lr) * N + bn + lc];
          Cs[lr * 136 + lc] = f2bf(v);
        }
      }
    }
    __syncthreads();
    constexpr int CHUNKS = BMT * 16;  // 16B chunks in the tile
#pragma unroll
    for (int c = 0; c < CHUNKS / 256; c++) {
      int id = c * 256 + tid;
      int row = id >> 4, ch = id & 15;
      int grow = bm + row;
      if (grow < M) {
        short8 val = *(const short8*)(Cs + row * 136 + ch * 8);
        int gcol = bn + ch * 8;
        if (OUTMODE == 1) {
          *(short8*)((ushort_t*)Cout + (size_t)grow * N + gcol) = val;
        } else {
          int b_ = grow / SEQ, t_ = grow - b_ * SEQ;
          int which = gcol / DMODEL;
          int hcol = gcol - which * DMODEL;
          int hh = hcol >> 6, d0 = hcol & 63;
          *(short8*)((ushort_t*)Cout +
                     ((((size_t)b_ * 3 + which) * HEADS + hh) * SEQ + t_) * 64 +
                     d0) = val;
        }
      }
    }
  }
}

// ---------------------------------------------------------------------------
// Zero the centroid accumulator (graph-safe)
__global__ __launch_bounds__(256) void zeroacc_kernel(int* __restrict__ g,
                                                      int n) {
  int i = blockIdx.x * 256 + threadIdx.x;
  if (i < n) g[i] = 0;
}

// ---------------------------------------------------------------------------
// Centroid v2a: partial histograms, 16 blocks per image, int atomics (determ.)
__global__ __launch_bounds__(256) void centroid_part_kernel(
    const int* __restrict__ seg, int* __restrict__ gacc) {
  __shared__ int cnt[RSEG], si[RSEG], sj[RSEG];
  int b = blockIdx.x, part = blockIdx.y, tid = threadIdx.x;
  for (int r = tid; r < RSEG; r += 256) { cnt[r] = 0; si[r] = 0; sj[r] = 0; }
  __syncthreads();
  const int* s = seg + (size_t)b * PIX;
  int p0 = part * PPP;
  for (int p = p0 + tid; p < p0 + PPP; p += 256) {
    int r = s[p];
    int i = p / IMG, j = p % IMG;
    atomicAdd(&cnt[r], 1);
    atomicAdd(&si[r], i);
    atomicAdd(&sj[r], j);
  }
  __syncthreads();
  for (int r = tid; r < RSEG; r += 256) {
    int c = cnt[r];
    if (c | si[r] | sj[r]) {
      int* g = gacc + ((size_t)b * RSEG + r) * 3;
      atomicAdd(&g[0], c);
      atomicAdd(&g[1], si[r]);
      atomicAdd(&g[2], sj[r]);
    }
  }
}
// Centroid v2b: finalize
__global__ __launch_bounds__(256) void centroid_fin_kernel(
    const int* __restrict__ gacc, float* __restrict__ cent) {
  int b = blockIdx.x, tid = threadIdx.x;
  for (int r = tid; r < RSEG; r += 256) {
    const int* g = gacc + ((size_t)b * RSEG + r) * 3;
    int c = g[0];
    float cx = 0.5f, cy = 0.5f;
    if (c > 0) {
      cx = ((float)g[2] / (float)IMG) / (float)c;
      cy = ((float)g[1] / (float)IMG) / (float)c;
    }
    cent[((size_t)b * RSEG + r) * 2 + 0] = cx;
    cent[((size_t)b * RSEG + r) * 2 + 1] = cy;
  }
}

// ---------------------------------------------------------------------------
// patch_seg[b,n] = seg[b, 8+hi*16, 8+wi*16]
__global__ __launch_bounds__(256) void patchseg_kernel(
    const int* __restrict__ seg, int* __restrict__ pseg) {
  int idx = blockIdx.x * 256 + threadIdx.x;
  if (idx >= BATCH * NPATCH) return;
  int n = idx % NPATCH, b = idx / NPATCH;
  int hi = n / HP, wi = n % HP;
  pseg[idx] = seg[(size_t)b * PIX + (8 + hi * PATCH) * IMG + (8 + wi * PATCH)];
}

// ---------------------------------------------------------------------------
// Build CSR lists of patches per (b, r): deterministic serial counting sort.
__global__ __launch_bounds__(64) void buildlists_kernel(
    const int* __restrict__ pseg, int* __restrict__ starts,
    int* __restrict__ lists) {
  __shared__ int cnt[RSEG];
  int b = blockIdx.x;
  if (threadIdx.x != 0) return;
  const int* ps = pseg + b * NPATCH;
  for (int r = 0; r < RSEG; r++) cnt[r] = 0;
  for (int n = 0; n < NPATCH; n++) cnt[ps[n]]++;
  int run = 0;
  int* st = starts + b * (RSEG + 1);
  for (int r = 0; r < RSEG; r++) {
    st[r] = run;
    int c = cnt[r];
    cnt[r] = run;  // becomes cursor
    run += c;
  }
  st[RSEG] = run;
  int* li = lists + b * NPATCH;
  for (int n = 0; n < NPATCH; n++) {
    int r = ps[n];
    li[cnt[r]++] = n;
  }
}

// ---------------------------------------------------------------------------
// Pool + assemble via CSR lists (avg 1 patch per segment).
__global__ __launch_bounds__(384) void pool_assemble_kernel(
    const float* __restrict__ emb, const float* __restrict__ cent,
    const int* __restrict__ starts, const int* __restrict__ lists,
    const float* __restrict__ cls_token, const float* __restrict__ cls_pos,
    const float* __restrict__ pos_W, const float* __restrict__ pos_b,
    float* __restrict__ h) {
  int t = blockIdx.x;
  int b = t / SEQ, s = t % SEQ;
  int d = threadIdx.x;
  float out;
  if (s == 0) {
    out = cls_token[d] + cls_pos[d];
  } else {
    int r = s - 1;
    int st = starts[b * (RSEG + 1) + r];
    int en = starts[b * (RSEG + 1) + r + 1];
    float acc = 0.f;
    for (int i = st; i < en; i++) {
      int n = lists[b * NPATCH + i];
      acc += emb[((size_t)b * NPATCH + n) * DMODEL + d];
    }
    int cnt = en - st;
    float pooled = acc / (float)(cnt > 0 ? cnt : 1);
    float cx = cent[((size_t)b * RSEG + r) * 2 + 0];
    float cy = cent[((size_t)b * RSEG + r) * 2 + 1];
    out = pooled + cx * pos_W[d] + cy * pos_W[DMODEL + d] + pos_b[d];
  }
  h[(size_t)t * DMODEL + d] = out;
}

// ---------------------------------------------------------------------------
// LayerNorm v2: one WAVE per row, 4 rows/block, float2 loads, shfl-only
// reduce (no LDS, no barrier). Grid = rows/4.
template <bool OUTBF16>
__global__ __launch_bounds__(256) void ln_kernel(
    const float* __restrict__ in, void* __restrict__ out,
    const float* __restrict__ w, const float* __restrict__ b, int inStride) {
  int wave = threadIdx.x >> 6, lane = threadIdx.x & 63;
  int row = blockIdx.x * 4 + wave;
  const float* xr = in + (size_t)row * inStride;
  float2 v0 = *(const float2*)(xr + lane * 2);
  float2 v1 = *(const float2*)(xr + 128 + lane * 2);
  float2 v2 = *(const float2*)(xr + 256 + lane * 2);
  float s = v0.x + v0.y + v1.x + v1.y + v2.x + v2.y;
  float s2 = v0.x * v0.x + v0.y * v0.y + v1.x * v1.x + v1.y * v1.y +
             v2.x * v2.x + v2.y * v2.y;
#pragma unroll
  for (int off = 32; off; off >>= 1) {
    s += __shfl_xor(s, off);
    s2 += __shfl_xor(s2, off);
  }
  float m = s / (float)DMODEL;
  float var = s2 / (float)DMODEL - m * m;
  float rs = rsqrtf(var + 1e-5f);
#pragma unroll
  for (int i = 0; i < 3; i++) {
    int d0 = i * 128 + lane * 2;
    float x0 = (i == 0) ? v0.x : (i == 1) ? v1.x : v2.x;
    float x1 = (i == 0) ? v0.y : (i == 1) ? v1.y : v2.y;
    float o0 = (x0 - m) * rs * w[d0] + b[d0];
    float o1 = (x1 - m) * rs * w[d0 + 1] + b[d0 + 1];
    if (OUTBF16) {
      uint_t pack = (uint_t)f2bf(o0) | ((uint_t)f2bf(o1) << 16);
      *(uint_t*)((ushort_t*)out + (size_t)row * DMODEL + d0) = pack;
    } else {
      float2 pk = {o0, o1};
      *(float2*)((float*)out + (size_t)row * DMODEL + d0) = pk;
    }
  }
}

// ---------------------------------------------------------------------------
// Banded attention v5: 4 queries per wave, register-cached K/V window.
__global__ __launch_bounds__(256) void attn_kernel(
    const ushort_t* __restrict__ qkvp, ushort_t* __restrict__ o) {
  int wave = threadIdx.x >> 6, lane = threadIdx.x & 63;
  int gi = blockIdx.x * 4 + wave;  // group index 0..51
  int hh = blockIdx.y, b = blockIdx.z;
  const size_t hstride = (size_t)HEADS * SEQ * 64;
  size_t base0 = ((size_t)b * 3 * HEADS + hh) * SEQ * 64;
  const ushort_t* Qh = qkvp + base0;
  const ushort_t* Kh = qkvp + base0 + hstride;
  const ushort_t* Vh = qkvp + base0 + 2 * hstride;
  if (gi < 49) {
    int q0 = 1 + gi * 4;
    int base = q0 - 4;
    if (base < 1) base = 1;
    int row = lane >> 2, dq = lane & 3;
    int key = (row == 0) ? 0 : base + row - 1;
    bool rowvalid = (key <= 196);
    int kaddr = rowvalid ? key : 196;  // clamp for safe address
    const uint_t* kp = (const uint_t*)(Kh + (size_t)kaddr * 64 + dq * 16);
    uint_t kf[8];
#pragma unroll
    for (int w = 0; w < 8; w++) kf[w] = kp[w];
    float v[16];
#pragma unroll
    for (int r = 0; r < 16; r++) {
      int kr = (r == 0) ? 0 : base + r - 1;
      if (kr > 196) kr = 196;
      v[r] = bf2f(Vh[(size_t)kr * 64 + lane]);
    }
#pragma unroll
    for (int i = 0; i < 4; i++) {
      int qi = q0 + i;
      const uint_t* qp = (const uint_t*)(Qh + (size_t)qi * 64 + dq * 16);
      float part = 0.f;
#pragma unroll
      for (int w = 0; w < 8; w++) {
        uint_t ka = kf[w], qa = qp[w];
        part += bf2f((ushort_t)(ka & 0xffff)) * bf2f((ushort_t)(qa & 0xffff));
        part += bf2f((ushort_t)(ka >> 16)) * bf2f((ushort_t)(qa >> 16));
      }
      part += __shfl_xor(part, 1);
      part += __shfl_xor(part, 2);
      int lo = qi - WIN;
      if (lo < 1) lo = 1;
      int hi = qi + WIN;
      if (hi > 196) hi = 196;
      bool valid = rowvalid && ((key == 0) || (key >= lo && key <= hi));
      float s = valid ? part * 0.125f : -1e30f;
      float mx = s;
      mx = fmaxf(mx, __shfl_xor(mx, 4));
      mx = fmaxf(mx, __shfl_xor(mx, 8));
      mx = fmaxf(mx, __shfl_xor(mx, 16));
      mx = fmaxf(mx, __shfl_xor(mx, 32));
      float p = valid ? expf(s - mx) : 0.f;
      float sum = p;
      sum += __shfl_xor(sum, 4);
      sum += __shfl_xor(sum, 8);
      sum += __shfl_xor(sum, 16);
      sum += __shfl_xor(sum, 32);
      float acc = 0.f;
#pragma unroll
      for (int r = 0; r < 16; r++) acc += __shfl(p, r * 4) * v[r];
      o[((size_t)(b * SEQ + qi)) * DMODEL + hh * HD + lane] = f2bf(acc / sum);
    }
  } else if (gi == 49) {
    const ushort_t* qr = Qh;  // CLS query
    float sc0 = -1e30f, sc1 = -1e30f, sc2 = -1e30f, sc3 = -1e30f;
#pragma unroll
    for (int c = 0; c < 4; c++) {
      int key = c * 64 + lane;
      float s = -1e30f;
      if (key < SEQ) {
        const ushort_t* kr = Kh + (size_t)key * 64;
        float acc = dot16bf(kr, qr) + dot16bf(kr + 16, qr + 16) +
                    dot16bf(kr + 32, qr + 32) + dot16bf(kr + 48, qr + 48);
        s = acc * 0.125f;
      }
      if (c == 0) sc0 = s; else if (c == 1) sc1 = s; else if (c == 2) sc2 = s; else sc3 = s;
    }
    float mx = fmaxf(fmaxf(sc0, sc1), fmaxf(sc2, sc3));
#pragma unroll
    for (int off = 32; off; off >>= 1) mx = fmaxf(mx, __shfl_xor(mx, off));
    float p0 = expf(sc0 - mx), p1 = expf(sc1 - mx);
    float p2 = expf(sc2 - mx), p3 = expf(sc3 - mx);
    float sum = p0 + p1 + p2 + p3;
#pragma unroll
    for (int off = 32; off; off >>= 1) sum += __shfl_xor(sum, off);
    float acc = 0.f;
#pragma unroll
    for (int c = 0; c < 4; c++) {
      float pc = (c == 0) ? p0 : (c == 1) ? p1 : (c == 2) ? p2 : p3;
      int jmax = (c < 3) ? 64 : (SEQ - 192);
      for (int jj = 0; jj < jmax; ++jj) {
        float pt = __shfl(pc, jj);
        acc += pt * bf2f(Vh[(size_t)(c * 64 + jj) * 64 + lane]);
      }
    }
    o[((size_t)(b * SEQ)) * DMODEL + hh * HD + lane] = f2bf(acc / sum);
  }
}

// ---------------------------------------------------------------------------
// Head
__global__ __launch_bounds__(256) void head_kernel(
    const float* __restrict__ hn, const float* __restrict__ W,
    const float* __restrict__ bias, float* __restrict__ out) {
  __shared__ float hs[DMODEL];
  int b = blockIdx.y;
  int c = blockIdx.x * 256 + threadIdx.x;
  for (int d = threadIdx.x; d < DMODEL; d += 256)
    hs[d] = hn[(size_t)b * DMODEL + d];
  __syncthreads();
  if (c >= CLS) return;
  float acc = bias[c];
  for (int d = 0; d < DMODEL; d++) acc += hs[d] * W[(size_t)d * CLS + c];
  out[(size_t)b * CLS + c] = acc;
}

// ---------------------------------------------------------------------------
extern "C" void kernel_launch(void* const* d_in, const int* in_sizes, int n_in,
                              void* d_out, int out_size, void* d_ws,
                              size_t ws_size, hipStream_t stream) {
  const float* x = (const float*)d_in[0];
  const int* seg = (const int*)d_in[1];
  const float* patch_W = (const float*)d_in[2];
  const float* patch_b = (const float*)d_in[3];
  const float* cls_token = (const float*)d_in[4];
  const float* pos_W = (const float*)d_in[5];
  const float* pos_b = (const float*)d_in[6];
  const float* cls_pos = (const float*)d_in[7];
  const float* ln1_w = (const float*)d_in[8];
  const float* ln1_b = (const float*)d_in[9];
  const float* qkv_W = (const float*)d_in[10];
  const float* qkv_b = (const float*)d_in[11];
  const float* proj_W = (const float*)d_in[12];
  const float* proj_b = (const float*)d_in[13];
  const float* ln2_w = (const float*)d_in[14];
  const float* ln2_b = (const float*)d_in[15];
  const float* mlp_W1 = (const float*)d_in[16];
  const float* mlp_b1 = (const float*)d_in[17];
  const float* mlp_W2 = (const float*)d_in[18];
  const float* mlp_b2 = (const float*)d_in[19];
  const float* norm_w = (const float*)d_in[20];
  const float* norm_b = (const float*)d_in[21];
  const float* head_W = (const float*)d_in[22];
  const float* head_b = (const float*)d_in[23];
  float* out = (float*)d_out;

  const int M0 = BATCH * NPATCH;  // 12544 = 196*64
  const int MT = BATCH * SEQ;     // 12608 = 197*64

  // ---- workspace layout ----
  char* ws = (char*)d_ws;
  size_t off = 0;
  auto alloc = [&](size_t bytes) { char* p = ws + off; off += (bytes + 255) & ~(size_t)255; return p; };
  ushort_t* patch_Wt = (ushort_t*)alloc((size_t)PATCHK * DMODEL * 2);
  ushort_t* qkv_Wt   = (ushort_t*)alloc((size_t)DEPTH * DMODEL * 3 * DMODEL * 2);
  ushort_t* proj_Wt  = (ushort_t*)alloc((size_t)DEPTH * DMODEL * DMODEL * 2);
  ushort_t* mlp1_Wt  = (ushort_t*)alloc((size_t)DEPTH * DMODEL * MLPD * 2);
  ushort_t* mlp2_Wt  = (ushort_t*)alloc((size_t)DEPTH * MLPD * DMODEL * 2);
  char* big = alloc((size_t)MT * MLPD * 2);          // xp_bf / mlph_bf
  ushort_t* xp_bf = (ushort_t*)big;
  ushort_t* mlph_bf = (ushort_t*)big;
  ushort_t* qkvb = (ushort_t*)alloc((size_t)MT * 3 * DMODEL * 2);  // permuted
  char* eo = alloc((size_t)M0 * DMODEL * 4);         // emb f32 / attno bf16
  float* emb = (float*)eo;
  ushort_t* attno = (ushort_t*)eo;
  float* h = (float*)alloc((size_t)MT * DMODEL * 4);
  ushort_t* z_bf = (ushort_t*)alloc((size_t)MT * DMODEL * 2);
  float* cent = (float*)alloc((size_t)BATCH * RSEG * 2 * 4);
  float* hn = (float*)alloc((size_t)BATCH * DMODEL * 4);
  int* pseg = (int*)alloc((size_t)BATCH * NPATCH * 4);
  int* starts = (int*)alloc((size_t)BATCH * (RSEG + 1) * 4);
  int* lists = (int*)alloc((size_t)BATCH * NPATCH * 4);
  int* gacc = (int*)alloc((size_t)BATCH * RSEG * 3 * 4);

  // ---- weight conversion+transpose (bf16, [N][K]) ----
  convtrans_kernel<<<dim3(DMODEL / 32, PATCHK / 32, 1), 256, 0, stream>>>(
      patch_W, patch_Wt, PATCHK, DMODEL);
  convtrans_kernel<<<dim3(3 * DMODEL / 32, DMODEL / 32, DEPTH), 256, 0, stream>>>(
      qkv_W, qkv_Wt, DMODEL, 3 * DMODEL);
  convtrans_kernel<<<dim3(DMODEL / 32, DMODEL / 32, DEPTH), 256, 0, stream>>>(
      proj_W, proj_Wt, DMODEL, DMODEL);
  convtrans_kernel<<<dim3(MLPD / 32, DMODEL / 32, DEPTH), 256, 0, stream>>>(
      mlp_W1, mlp1_Wt, DMODEL, MLPD);
  convtrans_kernel<<<dim3(DMODEL / 32, MLPD / 32, DEPTH), 256, 0, stream>>>(
      mlp_W2, mlp2_Wt, MLPD, DMODEL);

  // ---- front-end ----
  {
    int total4 = M0 * PATCHK / 4;
    patchify_kernel<<<(total4 + 255) / 256, 256, 0, stream>>>(x, xp_bf, total4);
  }
  gemm_gl<64, false, false, 0><<<(DMODEL / 128) * (M0 / 64), 256, 0, stream>>>(
      xp_bf, patch_Wt, patch_b, nullptr, emb, M0, DMODEL, PATCHK, DMODEL / 128);
  {
    int n = BATCH * RSEG * 3;
    zeroacc_kernel<<<(n + 255) / 256, 256, 0, stream>>>(gacc, n);
  }
  centroid_part_kernel<<<dim3(BATCH, CPARTS), 256, 0, stream>>>(seg, gacc);
  centroid_fin_kernel<<<BATCH, 256, 0, stream>>>(gacc, cent);
  patchseg_kernel<<<(M0 + 255) / 256, 256, 0, stream>>>(seg, pseg);
  buildlists_kernel<<<BATCH, 64, 0, stream>>>(pseg, starts, lists);
  pool_assemble_kernel<<<MT, 384, 0, stream>>>(emb, cent, starts, lists,
                                               cls_token, cls_pos, pos_W,
                                               pos_b, h);

  // ---- transformer layers ----
  int gy128 = (MT + 127) / 128;  // 99 (tail OOB reads covered by ws layout)
  int gy64 = MT / 64;            // 197 exact
  for (int l = 0; l < DEPTH; l++) {
    ln_kernel<true><<<MT / 4, 256, 0, stream>>>(h, z_bf, ln1_w + l * DMODEL,
                                                ln1_b + l * DMODEL, DMODEL);
    gemm_gl<128, false, false, 2><<<(3 * DMODEL / 128) * gy128, 256, 0, stream>>>(
        z_bf, qkv_Wt + (size_t)l * DMODEL * 3 * DMODEL, qkv_b + l * 3 * DMODEL,
        nullptr, qkvb, MT, 3 * DMODEL, DMODEL, 3 * DMODEL / 128);
    attn_kernel<<<dim3(13, HEADS, BATCH), 256, 0, stream>>>(qkvb, attno);
    gemm_gl<64, false, true, 0><<<(DMODEL / 128) * gy64, 256, 0, stream>>>(
        attno, proj_Wt + (size_t)l * DMODEL * DMODEL, proj_b + l * DMODEL, h,
        h, MT, DMODEL, DMODEL, DMODEL / 128);
    ln_kernel<true><<<MT / 4, 256, 0, stream>>>(h, z_bf, ln2_w + l * DMODEL,
                                                ln2_b + l * DMODEL, DMODEL);
    gemm_gl<128, true, false, 1><<<(MLPD / 128) * gy128, 256, 0, stream>>>(
        z_bf, mlp1_Wt + (size_t)l * DMODEL * MLPD, mlp_b1 + l * MLPD, nullptr,
        mlph_bf, MT, MLPD, DMODEL, MLPD / 128);
    gemm_gl<64, false, true, 0><<<(DMODEL / 128) * gy64, 256, 0, stream>>>(
        mlph_bf, mlp2_Wt + (size_t)l * MLPD * DMODEL, mlp_b2 + l * DMODEL, h,
        h, MT, DMODEL, MLPD, DMODEL / 128);
  }
  // ---- final LN (CLS rows only, 64 rows -> 16 blocks) + head ----
  ln_kernel<false><<<BATCH / 4, 256, 0, stream>>>(h, hn, norm_w, norm_b,
                                                  SEQ * DMODEL);
  head_kernel<<<dim3((CLS + 255) / 256, BATCH), 256, 0, stream>>>(
      hn, head_W, head_b, out);
}